// Round 1
// baseline (1207.397 us; speedup 1.0000x reference)
//
#include <hip/hip_runtime.h>
#include <math.h>

#define EPS 1e-6f

// ---- workspace float offsets ----
#define WS_ACC   0     // 20: [0..3]=sum e per reg, [4..19]=sum e*v
#define WS_CQ    32    // 4
#define WS_CK    40    // 4
#define WS_R1    64    // 512
#define WS_R2RAW 576   // 512
#define WS_R3RAW 1088  // 1024
#define WS_WQF   2112  // 2048  [D][4]
#define WS_WKF   4160  // 2048  [D][4]
#define WS_VALS  6208  // 512

__device__ __forceinline__ float silu_f(float x) { return x / (1.f + expf(-x)); }

// ============================================================ K0: fold Wq with register_keys, zero accumulators
__global__ void k0_prep(const float* __restrict__ Wq, const float* __restrict__ bq,
                        const float* __restrict__ rk, float* __restrict__ ws) {
    int t = threadIdx.x; // 512 threads
    if (t < 20) ws[WS_ACC + t] = 0.f;
    ws[WS_R2RAW + t] = 0.f;
    ws[WS_R3RAW + t] = 0.f;
    ws[WS_R3RAW + 512 + t] = 0.f;
    __shared__ float rks[16];
    if (t < 16) rks[t] = rk[t];
    __syncthreads();
    float a[4];
#pragma unroll
    for (int r = 0; r < 4; ++r) {
        float s = 0.f;
#pragma unroll
        for (int j = 0; j < 4; ++j) s += Wq[t * 16 + r * 4 + j] * rks[r * 4 + j];
        a[r] = s;
    }
    *(float4*)&ws[WS_WQF + t * 4] = make_float4(a[0], a[1], a[2], a[3]);
    if (t < 4) {
        float c = 0.f;
#pragma unroll
        for (int j = 0; j < 4; ++j) c += bq[t * 4 + j] * rks[t * 4 + j];
        ws[WS_CQ + t] = c;
    }
}

// ============================================================ K1: one pass over h -> softmax stats (sum e, sum e*v)
// Each wave processes 8 rows per pass; lane owns 8 contiguous d's.
__global__ __launch_bounds__(256, 2) void k1_att(const float* __restrict__ h,
                                                 const float* __restrict__ Wv,
                                                 float* __restrict__ ws, int N) {
    const int tid = threadIdx.x, wave = tid >> 6, lane = tid & 63;
    const int d0 = lane * 8;
    // preload folded Wq for my d's (8 x float4)
    float4 wq[8];
#pragma unroll
    for (int dd = 0; dd < 8; ++dd) wq[dd] = *(const float4*)&ws[WS_WQF + (d0 + dd) * 4];
    const float cq0 = ws[WS_CQ + 0], cq1 = ws[WS_CQ + 1], cq2 = ws[WS_CQ + 2], cq3 = ws[WS_CQ + 3];

    float acc16[16];
#pragma unroll
    for (int c = 0; c < 16; ++c) acc16[c] = 0.f;
    float accS[4] = {0.f, 0.f, 0.f, 0.f};

    for (int base = blockIdx.x * 32 + wave * 8; base < N; base += gridDim.x * 32) {
        // load 8 rows' chunks
        float hr[8][8];
#pragma unroll
        for (int rw = 0; rw < 8; ++rw) {
            int row = base + rw;
            if (row >= N) row = 0; // contribution zeroed via e below
            float4 a = *(const float4*)&h[row * 512 + d0];
            float4 b = *(const float4*)&h[row * 512 + d0 + 4];
            hr[rw][0] = a.x; hr[rw][1] = a.y; hr[rw][2] = a.z; hr[rw][3] = a.w;
            hr[rw][4] = b.x; hr[rw][5] = b.y; hr[rw][6] = b.z; hr[rw][7] = b.w;
        }
        // logit partials
        float lp[8][4];
#pragma unroll
        for (int rw = 0; rw < 8; ++rw) {
            float l0 = 0, l1 = 0, l2 = 0, l3 = 0;
#pragma unroll
            for (int dd = 0; dd < 8; ++dd) {
                float hv = hr[rw][dd];
                l0 += hv * wq[dd].x; l1 += hv * wq[dd].y;
                l2 += hv * wq[dd].z; l3 += hv * wq[dd].w;
            }
            lp[rw][0] = l0; lp[rw][1] = l1; lp[rw][2] = l2; lp[rw][3] = l3;
        }
        // butterfly reduce across 64 lanes (all lanes get totals)
#pragma unroll
        for (int m = 1; m < 64; m <<= 1) {
#pragma unroll
            for (int rw = 0; rw < 8; ++rw) {
#pragma unroll
                for (int r = 0; r < 4; ++r) lp[rw][r] += __shfl_xor(lp[rw][r], m, 64);
            }
        }
        // e = exp(logit); logits ~N(0,1) so no max-subtraction needed in fp32
        float e[8][4];
#pragma unroll
        for (int rw = 0; rw < 8; ++rw) {
            float e0 = expf((lp[rw][0] + cq0) * 0.5f);
            float e1 = expf((lp[rw][1] + cq1) * 0.5f);
            float e2 = expf((lp[rw][2] + cq2) * 0.5f);
            float e3 = expf((lp[rw][3] + cq3) * 0.5f);
            if (base + rw >= N) { e0 = e1 = e2 = e3 = 0.f; }
            e[rw][0] = e0; e[rw][1] = e1; e[rw][2] = e2; e[rw][3] = e3;
            if (lane == 0) { accS[0] += e0; accS[1] += e1; accS[2] += e2; accS[3] += e3; }
        }
        // gamma_r[d] = sum_rows e[row][r]*h[row][d]; then acc16 += gamma_r[d]*Wv[d][r*4+j]
#pragma unroll
        for (int dd = 0; dd < 8; ++dd) {
            float g0 = 0, g1 = 0, g2 = 0, g3 = 0;
#pragma unroll
            for (int rw = 0; rw < 8; ++rw) {
                float hv = hr[rw][dd];
                g0 += e[rw][0] * hv; g1 += e[rw][1] * hv;
                g2 += e[rw][2] * hv; g3 += e[rw][3] * hv;
            }
            const float* wvr = &Wv[(d0 + dd) * 16];
            float4 w0 = *(const float4*)&wvr[0];
            float4 w1 = *(const float4*)&wvr[4];
            float4 w2 = *(const float4*)&wvr[8];
            float4 w3 = *(const float4*)&wvr[12];
            acc16[0]  += g0 * w0.x; acc16[1]  += g0 * w0.y; acc16[2]  += g0 * w0.z; acc16[3]  += g0 * w0.w;
            acc16[4]  += g1 * w1.x; acc16[5]  += g1 * w1.y; acc16[6]  += g1 * w1.z; acc16[7]  += g1 * w1.w;
            acc16[8]  += g2 * w2.x; acc16[9]  += g2 * w2.y; acc16[10] += g2 * w2.z; acc16[11] += g2 * w2.w;
            acc16[12] += g3 * w3.x; acc16[13] += g3 * w3.y; acc16[14] += g3 * w3.z; acc16[15] += g3 * w3.w;
        }
    }
    // wave reduce
#pragma unroll
    for (int m = 1; m < 64; m <<= 1) {
#pragma unroll
        for (int c = 0; c < 16; ++c) acc16[c] += __shfl_xor(acc16[c], m, 64);
#pragma unroll
        for (int r = 0; r < 4; ++r) accS[r] += __shfl_xor(accS[r], m, 64);
    }
    __shared__ float red[4][20];
    if (lane == 0) {
#pragma unroll
        for (int r = 0; r < 4; ++r) red[wave][r] = accS[r];
#pragma unroll
        for (int c = 0; c < 16; ++c) red[wave][4 + c] = acc16[c];
    }
    __syncthreads();
    if (tid < 20) {
        float s = red[0][tid] + red[1][tid] + red[2][tid] + red[3][tid];
        atomicAdd(&ws[WS_ACC + tid], s);
    }
}

// ============================================================ K2a: register -> LN -> LN -> r1 = silu(r@W1+b1)
__global__ void k2a(const float* __restrict__ bv,
                    const float* __restrict__ lnrs, const float* __restrict__ lnrb,
                    const float* __restrict__ ln1s, const float* __restrict__ ln1b,
                    const float* __restrict__ W1, const float* __restrict__ b1,
                    float* __restrict__ ws) {
    __shared__ float rr[16];
    int t = threadIdx.x; // 512
    if (t == 0) {
        float x[16];
#pragma unroll
        for (int c = 0; c < 16; ++c) {
            float s = ws[WS_ACC + (c >> 2)];
            x[c] = ws[WS_ACC + 4 + c] / s + bv[c];
        }
#pragma unroll
        for (int pass = 0; pass < 2; ++pass) {
            const float* sc = pass ? ln1s : lnrs;
            const float* bi = pass ? ln1b : lnrb;
            float m = 0;
#pragma unroll
            for (int c = 0; c < 16; ++c) m += x[c];
            m *= (1.f / 16.f);
            float v = 0;
#pragma unroll
            for (int c = 0; c < 16; ++c) { float d = x[c] - m; v += d * d; }
            v *= (1.f / 16.f);
            float ri = rsqrtf(v + EPS);
#pragma unroll
            for (int c = 0; c < 16; ++c) x[c] = (x[c] - m) * ri * sc[c] + bi[c];
        }
#pragma unroll
        for (int c = 0; c < 16; ++c) rr[c] = x[c];
    }
    __syncthreads();
    float a = b1[t];
#pragma unroll
    for (int i = 0; i < 16; ++i) a += rr[i] * W1[i * 512 + t];
    ws[WS_R1 + t] = silu_f(a);
}

// ============================================================ K2b: r2raw += r1 @ W2   (16 blocks x 256)
__global__ void k2b(const float* __restrict__ W2, float* __restrict__ ws) {
    __shared__ float r1s[32];
    int t = threadIdx.x, k0 = blockIdx.x * 32;
    if (t < 32) r1s[t] = ws[WS_R1 + k0 + t];
    __syncthreads();
#pragma unroll
    for (int half = 0; half < 2; ++half) {
        int col = t + half * 256;
        float a = 0.f;
#pragma unroll
        for (int kk = 0; kk < 32; ++kk) a += r1s[kk] * W2[(k0 + kk) * 512 + col];
        atomicAdd(&ws[WS_R2RAW + col], a);
    }
}

// ============================================================ K2c: r3raw += silu(r2+b2) @ W3  (32 blocks x 256)
__global__ void k2c(const float* __restrict__ b2, const float* __restrict__ W3,
                    float* __restrict__ ws) {
    __shared__ float r2s[16];
    int t = threadIdx.x, k0 = blockIdx.x * 16;
    if (t < 16) {
        float x = ws[WS_R2RAW + k0 + t] + b2[k0 + t];
        r2s[t] = silu_f(x);
    }
    __syncthreads();
#pragma unroll
    for (int q = 0; q < 4; ++q) {
        int col = t + q * 256;
        float a = 0.f;
#pragma unroll
        for (int kk = 0; kk < 16; ++kk) a += r2s[kk] * W3[(k0 + kk) * 1024 + col];
        atomicAdd(&ws[WS_R3RAW + col], a);
    }
}

// ============================================================ K2d: fold Wk with queries; emit values, ck (32 blocks x 256)
__global__ void k2d(const float* __restrict__ Wk, const float* __restrict__ bk,
                    const float* __restrict__ b3, float* __restrict__ ws) {
    __shared__ float qv[512];
    int t = threadIdx.x;
    qv[t] = ws[WS_R3RAW + t] + b3[t];
    qv[t + 256] = ws[WS_R3RAW + t + 256] + b3[t + 256];
    __syncthreads();
    int wave = t >> 6, lane = t & 63;
#pragma unroll
    for (int it = 0; it < 4; ++it) {
        int D = it * 128 + blockIdx.x * 4 + wave;
        float4 w0 = *(const float4*)&Wk[D * 512 + lane * 4];
        float4 w1 = *(const float4*)&Wk[D * 512 + 256 + lane * 4];
        float4 q0 = *(const float4*)&qv[lane * 4];
        float4 q1 = *(const float4*)&qv[256 + lane * 4];
        float pa = w0.x * q0.x + w0.y * q0.y + w0.z * q0.z + w0.w * q0.w;
        float pb = w1.x * q1.x + w1.y * q1.y + w1.z * q1.z + w1.w * q1.w;
#pragma unroll
        for (int m = 1; m < 32; m <<= 1) {
            pa += __shfl_xor(pa, m, 64);
            pb += __shfl_xor(pb, m, 64);
        }
        if (lane == 0)  { ws[WS_WKF + D * 4 + 0] = pa; ws[WS_WKF + D * 4 + 2] = pb; }
        if (lane == 32) { ws[WS_WKF + D * 4 + 1] = pa; ws[WS_WKF + D * 4 + 3] = pb; }
    }
    if (blockIdx.x == 0) {
        ws[WS_VALS + t] = ws[WS_R3RAW + 512 + t] + b3[512 + t];
        ws[WS_VALS + 256 + t] = ws[WS_R3RAW + 768 + t] + b3[768 + t];
        if (t < 4) {
            float c = 0.f;
            for (int j = 0; j < 128; ++j) c += bk[t * 128 + j] * qv[t * 128 + j];
            ws[WS_CK + t] = c;
        }
    }
}

// ============================================================ K5: fused main pass (32 rows / block)
// attention(folded) + LN2 in LDS, then 32x512x512 fp32 GEMM (8x8 per thread), silu+residual+LN3, store.
__global__ __launch_bounds__(256, 2) void k5_main(
    const float* __restrict__ h, const float* __restrict__ ws,
    const float* __restrict__ ln2s, const float* __restrict__ ln2b,
    const float* __restrict__ Wm, const float* __restrict__ bm,
    const float* __restrict__ ln3s, const float* __restrict__ ln3b,
    float* __restrict__ out, int N) {
    __shared__ float hs[32 * 516];   // padded rows (516) to spread banks
    __shared__ float wkf[2048];      // [d][4]
    __shared__ float pv[512];
    __shared__ float cks[4];
    const int t = threadIdx.x;
    const int rb = blockIdx.x * 32;

#pragma unroll
    for (int i = 0; i < 8; ++i) wkf[t + i * 256] = ws[WS_WKF + t + i * 256];
    pv[t] = ws[WS_VALS + t];
    pv[t + 256] = ws[WS_VALS + t + 256];
    if (t < 4) cks[t] = ws[WS_CK + t];

    // load h tile (coalesced float4)
#pragma unroll
    for (int i = 0; i < 16; ++i) {
        int f = t + i * 256;           // float4 index within tile
        int row = f >> 7, c4 = f & 127;
        int grow = rb + row; if (grow >= N) grow = N - 1;
        float4 v = *(const float4*)&h[grow * 512 + c4 * 4];
        *(float4*)&hs[row * 516 + c4 * 4] = v;
    }
    __syncthreads();

    // ---- step 2: folded attention + LN2 (8 threads per row, strided d) ----
    {
        const int row = t >> 3, sub = t & 7;
        float g0 = 0, g1 = 0, g2 = 0, g3 = 0;
#pragma unroll
        for (int i = 0; i < 64; ++i) {
            int d = sub + i * 8;
            float hv = hs[row * 516 + d];
            float4 w = *(const float4*)&wkf[d * 4];
            g0 += hv * w.x; g1 += hv * w.y; g2 += hv * w.z; g3 += hv * w.w;
        }
#pragma unroll
        for (int m = 1; m < 8; m <<= 1) {
            g0 += __shfl_xor(g0, m, 64); g1 += __shfl_xor(g1, m, 64);
            g2 += __shfl_xor(g2, m, 64); g3 += __shfl_xor(g3, m, 64);
        }
        const float sc = 0.08838834764831845f; // 1/sqrt(128)
        g0 = (g0 + cks[0]) * sc; g1 = (g1 + cks[1]) * sc;
        g2 = (g2 + cks[2]) * sc; g3 = (g3 + cks[3]) * sc;
        float mx = fmaxf(fmaxf(g0, g1), fmaxf(g2, g3));
        float e0 = expf(g0 - mx), e1 = expf(g1 - mx), e2 = expf(g2 - mx), e3 = expf(g3 - mx);
        float inv = 1.f / (e0 + e1 + e2 + e3);
        float a0 = e0 * inv, a1 = e1 * inv, a2 = e2 * inv, a3 = e3 * inv;

        float sum = 0.f, ssq = 0.f;
#pragma unroll
        for (int r = 0; r < 4; ++r) {
            float ar = (r == 0) ? a0 : (r == 1) ? a1 : (r == 2) ? a2 : a3;
#pragma unroll
            for (int ii = 0; ii < 16; ++ii) {
                int d = sub + (r * 16 + ii) * 8;
                float tv = hs[row * 516 + d] + ar * pv[d];
                sum += tv; ssq += tv * tv;
            }
        }
#pragma unroll
        for (int m = 1; m < 8; m <<= 1) {
            sum += __shfl_xor(sum, m, 64); ssq += __shfl_xor(ssq, m, 64);
        }
        float mean = sum * (1.f / 512.f);
        float var = ssq * (1.f / 512.f) - mean * mean;
        float rin = rsqrtf(fmaxf(var, 0.f) + EPS);
#pragma unroll
        for (int r = 0; r < 4; ++r) {
            float ar = (r == 0) ? a0 : (r == 1) ? a1 : (r == 2) ? a2 : a3;
#pragma unroll
            for (int ii = 0; ii < 16; ++ii) {
                int d = sub + (r * 16 + ii) * 8;
                float tv = hs[row * 516 + d] + ar * pv[d];
                hs[row * 516 + d] = (tv - mean) * rin * ln2s[d] + ln2b[d];
            }
        }
    }
    __syncthreads();

    // ---- step 3: mlp GEMM, 8x8 per thread; cols split {cg*4..+3} U {256+cg*4..+3} ----
    const int rg = t >> 6, cg = t & 63;
    const int r0 = rg * 8;
    const float4* Wm4 = (const float4*)Wm;
    float acc[8][8];
#pragma unroll
    for (int i = 0; i < 8; ++i)
#pragma unroll
        for (int j = 0; j < 8; ++j) acc[i][j] = 0.f;

    for (int k = 0; k < 512; k += 4) {
        float4 a4[8];
#pragma unroll
        for (int ri = 0; ri < 8; ++ri) a4[ri] = *(const float4*)&hs[(r0 + ri) * 516 + k];
#pragma unroll
        for (int u = 0; u < 4; ++u) {
            float4 b0 = Wm4[(k + u) * 128 + cg];
            float4 b1 = Wm4[(k + u) * 128 + 64 + cg];
#pragma unroll
            for (int ri = 0; ri < 8; ++ri) {
                float av = (u == 0) ? a4[ri].x : (u == 1) ? a4[ri].y : (u == 2) ? a4[ri].z : a4[ri].w;
                acc[ri][0] += av * b0.x; acc[ri][1] += av * b0.y;
                acc[ri][2] += av * b0.z; acc[ri][3] += av * b0.w;
                acc[ri][4] += av * b1.x; acc[ri][5] += av * b1.y;
                acc[ri][6] += av * b1.z; acc[ri][7] += av * b1.w;
            }
        }
    }

    // ---- epilogue: silu + residual + LN3 + store ----
    float4 bm0 = *(const float4*)&bm[cg * 4];
    float4 bm1 = *(const float4*)&bm[256 + cg * 4];
    float4 s30 = *(const float4*)&ln3s[cg * 4];
    float4 s31 = *(const float4*)&ln3s[256 + cg * 4];
    float4 b30 = *(const float4*)&ln3b[cg * 4];
    float4 b31 = *(const float4*)&ln3b[256 + cg * 4];
#pragma unroll
    for (int ri = 0; ri < 8; ++ri) {
        int row = r0 + ri;
        float4 h20 = *(const float4*)&hs[row * 516 + cg * 4];
        float4 h21 = *(const float4*)&hs[row * 516 + 256 + cg * 4];
        float tv0 = h20.x + silu_f(acc[ri][0] + bm0.x);
        float tv1 = h20.y + silu_f(acc[ri][1] + bm0.y);
        float tv2 = h20.z + silu_f(acc[ri][2] + bm0.z);
        float tv3 = h20.w + silu_f(acc[ri][3] + bm0.w);
        float tv4 = h21.x + silu_f(acc[ri][4] + bm1.x);
        float tv5 = h21.y + silu_f(acc[ri][5] + bm1.y);
        float tv6 = h21.z + silu_f(acc[ri][6] + bm1.z);
        float tv7 = h21.w + silu_f(acc[ri][7] + bm1.w);
        float sum = tv0 + tv1 + tv2 + tv3 + tv4 + tv5 + tv6 + tv7;
        float ssq = tv0 * tv0 + tv1 * tv1 + tv2 * tv2 + tv3 * tv3 +
                    tv4 * tv4 + tv5 * tv5 + tv6 * tv6 + tv7 * tv7;
#pragma unroll
        for (int m = 1; m < 64; m <<= 1) {
            sum += __shfl_xor(sum, m, 64);
            ssq += __shfl_xor(ssq, m, 64);
        }
        float mean = sum * (1.f / 512.f);
        float var = ssq * (1.f / 512.f) - mean * mean;
        float rin = rsqrtf(fmaxf(var, 0.f) + EPS);
        float4 o0, o1;
        o0.x = (tv0 - mean) * rin * s30.x + b30.x;
        o0.y = (tv1 - mean) * rin * s30.y + b30.y;
        o0.z = (tv2 - mean) * rin * s30.z + b30.z;
        o0.w = (tv3 - mean) * rin * s30.w + b30.w;
        o1.x = (tv4 - mean) * rin * s31.x + b31.x;
        o1.y = (tv5 - mean) * rin * s31.y + b31.y;
        o1.z = (tv6 - mean) * rin * s31.z + b31.z;
        o1.w = (tv7 - mean) * rin * s31.w + b31.w;
        if (rb + row < N) {
            *(float4*)&out[(rb + row) * 512 + cg * 4] = o0;
            *(float4*)&out[(rb + row) * 512 + 256 + cg * 4] = o1;
        }
    }
}

// ============================================================ launcher
extern "C" void kernel_launch(void* const* d_in, const int* in_sizes, int n_in,
                              void* d_out, int out_size, void* d_ws, size_t ws_size,
                              hipStream_t stream) {
    const float* h    = (const float*)d_in[0];
    // d_in[1] = spin (unused by the reference)
    const float* rk   = (const float*)d_in[2];
    const float* Wq   = (const float*)d_in[3];
    const float* bq   = (const float*)d_in[4];
    const float* Wv   = (const float*)d_in[5];
    const float* bv   = (const float*)d_in[6];
    const float* lnrs = (const float*)d_in[7];
    const float* lnrb = (const float*)d_in[8];
    const float* ln1s = (const float*)d_in[9];
    const float* ln1b = (const float*)d_in[10];
    const float* W1   = (const float*)d_in[11];
    const float* b1   = (const float*)d_in[12];
    const float* W2   = (const float*)d_in[13];
    const float* b2   = (const float*)d_in[14];
    const float* W3   = (const float*)d_in[15];
    const float* b3   = (const float*)d_in[16];
    const float* Wk   = (const float*)d_in[17];
    const float* bk   = (const float*)d_in[18];
    const float* ln2s = (const float*)d_in[19];
    const float* ln2b = (const float*)d_in[20];
    const float* Wm   = (const float*)d_in[21];
    const float* bm   = (const float*)d_in[22];
    const float* ln3s = (const float*)d_in[23];
    const float* ln3b = (const float*)d_in[24];
    float* out = (float*)d_out;
    float* ws  = (float*)d_ws;
    const int N = in_sizes[0] / 512;

    k0_prep<<<1, 512, 0, stream>>>(Wq, bq, rk, ws);
    k1_att<<<1024, 256, 0, stream>>>(h, Wv, ws, N);
    k2a<<<1, 512, 0, stream>>>(bv, lnrs, lnrb, ln1s, ln1b, W1, b1, ws);
    k2b<<<16, 256, 0, stream>>>(W2, ws);
    k2c<<<32, 256, 0, stream>>>(b2, W3, ws);
    k2d<<<32, 256, 0, stream>>>(Wk, bk, b3, ws);
    k5_main<<<(N + 31) / 32, 256, 0, stream>>>(h, ws, ln2s, ln2b, Wm, bm, ln3s, ln3b, out, N);
}

// Round 5
// 885.471 us; speedup vs baseline: 1.3636x; 1.3636x over previous
//
#include <hip/hip_runtime.h>
#include <math.h>

#define EPS 1e-6f

// ---- workspace float offsets ----
#define WS_CQ    32    // 4
#define WS_CK    40    // 4
#define WS_R1    64    // 512
#define WS_R2RAW 576   // 512
#define WS_R3RAW 1088  // 1024
#define WS_WQF   2112  // 2048  [D][4]
#define WS_WKF   4160  // 2048  [D][4]
#define WS_VALS  6208  // 512
#define WS_PART  6720  // 256*20 = 5120 (k1 per-block partials)
#define WS_BH    16384 // 512KB as floats: 131072
#define WS_BL    147456// 131072

typedef __attribute__((ext_vector_type(8))) short bf16x8;
typedef __attribute__((ext_vector_type(4))) float f32x4;

__device__ __forceinline__ float silu_f(float x) { return x / (1.f + expf(-x)); }

__device__ __forceinline__ unsigned short bf16_rne(float x) {
    unsigned u = __float_as_uint(x);
    unsigned r = u + 0x7fffu + ((u >> 16) & 1u);
    return (unsigned short)(r >> 16);
}
__device__ __forceinline__ float bf16_to_f(unsigned short s) {
    return __uint_as_float(((unsigned)s) << 16);
}

// ============================================================ K0: fold Wq with register_keys, zero accumulators
__global__ void k0_prep(const float* __restrict__ Wq, const float* __restrict__ bq,
                        const float* __restrict__ rk, float* __restrict__ ws) {
    int t = threadIdx.x; // 512 threads
    ws[WS_R2RAW + t] = 0.f;
    ws[WS_R3RAW + t] = 0.f;
    ws[WS_R3RAW + 512 + t] = 0.f;
    __shared__ float rks[16];
    if (t < 16) rks[t] = rk[t];
    __syncthreads();
    float a[4];
#pragma unroll
    for (int r = 0; r < 4; ++r) {
        float s = 0.f;
#pragma unroll
        for (int j = 0; j < 4; ++j) s += Wq[t * 16 + r * 4 + j] * rks[r * 4 + j];
        a[r] = s;
    }
    *(float4*)&ws[WS_WQF + t * 4] = make_float4(a[0], a[1], a[2], a[3]);
    if (t < 4) {
        float c = 0.f;
#pragma unroll
        for (int j = 0; j < 4; ++j) c += bq[t * 4 + j] * rks[t * 4 + j];
        ws[WS_CQ + t] = c;
    }
}

// ============================================================ K1: one pass over h -> softmax stats partials (no atomics)
__global__ __launch_bounds__(256, 2) void k1_att(const float* __restrict__ h,
                                                 const float* __restrict__ Wv,
                                                 float* __restrict__ ws, int N) {
    const int tid = threadIdx.x, wave = tid >> 6, lane = tid & 63;
    const int d0 = lane * 8;
    float4 wq[8];
#pragma unroll
    for (int dd = 0; dd < 8; ++dd) wq[dd] = *(const float4*)&ws[WS_WQF + (d0 + dd) * 4];
    const float cq0 = ws[WS_CQ + 0], cq1 = ws[WS_CQ + 1], cq2 = ws[WS_CQ + 2], cq3 = ws[WS_CQ + 3];

    float acc16[16];
#pragma unroll
    for (int c = 0; c < 16; ++c) acc16[c] = 0.f;
    float accS[4] = {0.f, 0.f, 0.f, 0.f};

    for (int base = blockIdx.x * 32 + wave * 8; base < N; base += gridDim.x * 32) {
        float hr[8][8];
#pragma unroll
        for (int rw = 0; rw < 8; ++rw) {
            int row = base + rw;
            if (row >= N) row = 0;
            float4 a = *(const float4*)&h[(size_t)row * 512 + d0];
            float4 b = *(const float4*)&h[(size_t)row * 512 + d0 + 4];
            hr[rw][0] = a.x; hr[rw][1] = a.y; hr[rw][2] = a.z; hr[rw][3] = a.w;
            hr[rw][4] = b.x; hr[rw][5] = b.y; hr[rw][6] = b.z; hr[rw][7] = b.w;
        }
        float lp[8][4];
#pragma unroll
        for (int rw = 0; rw < 8; ++rw) {
            float l0 = 0, l1 = 0, l2 = 0, l3 = 0;
#pragma unroll
            for (int dd = 0; dd < 8; ++dd) {
                float hv = hr[rw][dd];
                l0 += hv * wq[dd].x; l1 += hv * wq[dd].y;
                l2 += hv * wq[dd].z; l3 += hv * wq[dd].w;
            }
            lp[rw][0] = l0; lp[rw][1] = l1; lp[rw][2] = l2; lp[rw][3] = l3;
        }
#pragma unroll
        for (int m = 1; m < 64; m <<= 1) {
#pragma unroll
            for (int rw = 0; rw < 8; ++rw) {
#pragma unroll
                for (int r = 0; r < 4; ++r) lp[rw][r] += __shfl_xor(lp[rw][r], m, 64);
            }
        }
        float e[8][4];
#pragma unroll
        for (int rw = 0; rw < 8; ++rw) {
            float e0 = expf((lp[rw][0] + cq0) * 0.5f);
            float e1 = expf((lp[rw][1] + cq1) * 0.5f);
            float e2 = expf((lp[rw][2] + cq2) * 0.5f);
            float e3 = expf((lp[rw][3] + cq3) * 0.5f);
            if (base + rw >= N) { e0 = e1 = e2 = e3 = 0.f; }
            e[rw][0] = e0; e[rw][1] = e1; e[rw][2] = e2; e[rw][3] = e3;
            if (lane == 0) { accS[0] += e0; accS[1] += e1; accS[2] += e2; accS[3] += e3; }
        }
#pragma unroll
        for (int dd = 0; dd < 8; ++dd) {
            float g0 = 0, g1 = 0, g2 = 0, g3 = 0;
#pragma unroll
            for (int rw = 0; rw < 8; ++rw) {
                float hv = hr[rw][dd];
                g0 += e[rw][0] * hv; g1 += e[rw][1] * hv;
                g2 += e[rw][2] * hv; g3 += e[rw][3] * hv;
            }
            const float* wvr = &Wv[(d0 + dd) * 16];
            float4 w0 = *(const float4*)&wvr[0];
            float4 w1 = *(const float4*)&wvr[4];
            float4 w2 = *(const float4*)&wvr[8];
            float4 w3 = *(const float4*)&wvr[12];
            acc16[0]  += g0 * w0.x; acc16[1]  += g0 * w0.y; acc16[2]  += g0 * w0.z; acc16[3]  += g0 * w0.w;
            acc16[4]  += g1 * w1.x; acc16[5]  += g1 * w1.y; acc16[6]  += g1 * w1.z; acc16[7]  += g1 * w1.w;
            acc16[8]  += g2 * w2.x; acc16[9]  += g2 * w2.y; acc16[10] += g2 * w2.z; acc16[11] += g2 * w2.w;
            acc16[12] += g3 * w3.x; acc16[13] += g3 * w3.y; acc16[14] += g3 * w3.z; acc16[15] += g3 * w3.w;
        }
    }
#pragma unroll
    for (int m = 1; m < 64; m <<= 1) {
#pragma unroll
        for (int c = 0; c < 16; ++c) acc16[c] += __shfl_xor(acc16[c], m, 64);
#pragma unroll
        for (int r = 0; r < 4; ++r) accS[r] += __shfl_xor(accS[r], m, 64);
    }
    __shared__ float red[4][20];
    if (lane == 0) {
#pragma unroll
        for (int r = 0; r < 4; ++r) red[wave][r] = accS[r];
#pragma unroll
        for (int c = 0; c < 16; ++c) red[wave][4 + c] = acc16[c];
    }
    __syncthreads();
    if (tid < 20) {
        float s = red[0][tid] + red[1][tid] + red[2][tid] + red[3][tid];
        ws[WS_PART + blockIdx.x * 20 + tid] = s;
    }
}

// ============================================================ K2a: reduce partials; register -> LN -> LN -> r1
__global__ void k2a(const float* __restrict__ bv,
                    const float* __restrict__ lnrs, const float* __restrict__ lnrb,
                    const float* __restrict__ ln1s, const float* __restrict__ ln1b,
                    const float* __restrict__ W1, const float* __restrict__ b1,
                    float* __restrict__ ws) {
    __shared__ float rr[16];
    __shared__ float accs[20];
    int t = threadIdx.x; // 512
    if (t < 20) {
        float s = 0.f;
#pragma unroll 8
        for (int b = 0; b < 256; ++b) s += ws[WS_PART + b * 20 + t];
        accs[t] = s;
    }
    __syncthreads();
    if (t == 0) {
        float x[16];
#pragma unroll
        for (int c = 0; c < 16; ++c) x[c] = accs[4 + c] / accs[c >> 2] + bv[c];
#pragma unroll
        for (int pass = 0; pass < 2; ++pass) {
            const float* sc = pass ? ln1s : lnrs;
            const float* bi = pass ? ln1b : lnrb;
            float m = 0;
#pragma unroll
            for (int c = 0; c < 16; ++c) m += x[c];
            m *= (1.f / 16.f);
            float v = 0;
#pragma unroll
            for (int c = 0; c < 16; ++c) { float d = x[c] - m; v += d * d; }
            v *= (1.f / 16.f);
            float ri = rsqrtf(v + EPS);
#pragma unroll
            for (int c = 0; c < 16; ++c) x[c] = (x[c] - m) * ri * sc[c] + bi[c];
        }
#pragma unroll
        for (int c = 0; c < 16; ++c) rr[c] = x[c];
    }
    __syncthreads();
    float a = b1[t];
#pragma unroll
    for (int i = 0; i < 16; ++i) a += rr[i] * W1[i * 512 + t];
    ws[WS_R1 + t] = silu_f(a);
}

// ============================================================ K2b: r2raw += r1 @ W2   (16 blocks x 256)
__global__ void k2b(const float* __restrict__ W2, float* __restrict__ ws) {
    __shared__ float r1s[32];
    int t = threadIdx.x, k0 = blockIdx.x * 32;
    if (t < 32) r1s[t] = ws[WS_R1 + k0 + t];
    __syncthreads();
#pragma unroll
    for (int half = 0; half < 2; ++half) {
        int col = t + half * 256;
        float a = 0.f;
#pragma unroll
        for (int kk = 0; kk < 32; ++kk) a += r1s[kk] * W2[(k0 + kk) * 512 + col];
        atomicAdd(&ws[WS_R2RAW + col], a);
    }
}

// ============================================================ K2c: r3raw += silu(r2+b2) @ W3  (32 blocks x 256)
__global__ void k2c(const float* __restrict__ b2, const float* __restrict__ W3,
                    float* __restrict__ ws) {
    __shared__ float r2s[16];
    int t = threadIdx.x, k0 = blockIdx.x * 16;
    if (t < 16) {
        float x = ws[WS_R2RAW + k0 + t] + b2[k0 + t];
        r2s[t] = silu_f(x);
    }
    __syncthreads();
#pragma unroll
    for (int q = 0; q < 4; ++q) {
        int col = t + q * 256;
        float a = 0.f;
#pragma unroll
        for (int kk = 0; kk < 16; ++kk) a += r2s[kk] * W3[(k0 + kk) * 1024 + col];
        atomicAdd(&ws[WS_R3RAW + col], a);
    }
}

// ============================================================ K2d: fold Wk with queries; emit values, ck (32 blocks x 256)
__global__ void k2d(const float* __restrict__ Wk, const float* __restrict__ bk,
                    const float* __restrict__ b3, float* __restrict__ ws) {
    __shared__ float qv[512];
    int t = threadIdx.x;
    qv[t] = ws[WS_R3RAW + t] + b3[t];
    qv[t + 256] = ws[WS_R3RAW + t + 256] + b3[t + 256];
    __syncthreads();
    int wave = t >> 6, lane = t & 63;
#pragma unroll
    for (int it = 0; it < 4; ++it) {
        int D = it * 128 + blockIdx.x * 4 + wave;
        float4 w0 = *(const float4*)&Wk[D * 512 + lane * 4];
        float4 w1 = *(const float4*)&Wk[D * 512 + 256 + lane * 4];
        float4 q0 = *(const float4*)&qv[lane * 4];
        float4 q1 = *(const float4*)&qv[256 + lane * 4];
        float pa = w0.x * q0.x + w0.y * q0.y + w0.z * q0.z + w0.w * q0.w;
        float pb = w1.x * q1.x + w1.y * q1.y + w1.z * q1.z + w1.w * q1.w;
#pragma unroll
        for (int m = 1; m < 32; m <<= 1) {
            pa += __shfl_xor(pa, m, 64);
            pb += __shfl_xor(pb, m, 64);
        }
        if (lane == 0)  { ws[WS_WKF + D * 4 + 0] = pa; ws[WS_WKF + D * 4 + 2] = pb; }
        if (lane == 32) { ws[WS_WKF + D * 4 + 1] = pa; ws[WS_WKF + D * 4 + 3] = pb; }
    }
    if (blockIdx.x == 0) {
        ws[WS_VALS + t] = ws[WS_R3RAW + 512 + t] + b3[512 + t];
        ws[WS_VALS + 256 + t] = ws[WS_R3RAW + 768 + t] + b3[768 + t];
        if (t < 4) {
            float c = 0.f;
            for (int j = 0; j < 128; ++j) c += bk[t * 128 + j] * qv[t * 128 + j];
            ws[WS_CK + t] = c;
        }
    }
}

// ============================================================ K3: convert Wm -> fragment-ordered bf16 hi/lo
// frag element: Wm[ks*32 + (lane>>4)*8 + j][ct*16 + (lane&15)], stored at ((ks*32+ct)*64+lane)*8 + j
__global__ void k3_conv(const float* __restrict__ Wm, float* __restrict__ ws) {
    int g = blockIdx.x * 256 + threadIdx.x;      // 128 blocks x 256
    int ks = g >> 11, ct = (g >> 6) & 31, lane = g & 63;
    int kb = ks * 32 + (lane >> 4) * 8;
    int n = ct * 16 + (lane & 15);
    bf16x8 vh, vl;
#pragma unroll
    for (int j = 0; j < 8; ++j) {
        float x = Wm[(kb + j) * 512 + n];
        unsigned short hs = bf16_rne(x);
        float r = x - bf16_to_f(hs);
        vh[j] = (short)hs;
        vl[j] = (short)bf16_rne(r);
    }
    unsigned short* BH = (unsigned short*)&ws[WS_BH];
    unsigned short* BL = (unsigned short*)&ws[WS_BL];
    *(bf16x8*)&BH[g * 8] = vh;
    *(bf16x8*)&BL[g * 8] = vl;
}

// ============================================================ K5: fused main pass, 64 rows/block, split-bf16 MFMA GEMM
#define AP 520  // padded A-tile row length in bf16 elems (stride 1040B -> ~2-way bank = free)
__global__ __launch_bounds__(512, 2) void k5_main(
    const float* __restrict__ h, const float* __restrict__ ws,
    const float* __restrict__ ln2s, const float* __restrict__ ln2b,
    const float* __restrict__ bm,
    const float* __restrict__ ln3s, const float* __restrict__ ln3b,
    float* __restrict__ out, int N) {
    __shared__ unsigned short Ahi[64 * AP];
    __shared__ unsigned short Alo[64 * AP];
    __shared__ float rpart[64][16];  // [row][wave*2 + {sum,ssq}]
    const int t = threadIdx.x;
    const int rb = blockIdx.x * 64;

    // ---------------- phase 1: attention + LN2, h kept in registers ----------------
    {
        const int row = t >> 3, sub = t & 7;
        int grow = rb + row; if (grow >= N) grow = N - 1;
        const float* hrow = &h[(size_t)grow * 512 + sub * 64];
        float hv[64];
#pragma unroll
        for (int i = 0; i < 16; ++i) {
            float4 v = *(const float4*)&hrow[i * 4];
            hv[i * 4] = v.x; hv[i * 4 + 1] = v.y; hv[i * 4 + 2] = v.z; hv[i * 4 + 3] = v.w;
        }
        // logits (folded Wk·queries from ws)
        float l0 = 0, l1 = 0, l2 = 0, l3 = 0;
        const float4* wk4 = (const float4*)&ws[WS_WKF + sub * 64 * 4];
#pragma unroll
        for (int i = 0; i < 64; ++i) {
            float4 w = wk4[i];
            float x = hv[i];
            l0 += x * w.x; l1 += x * w.y; l2 += x * w.z; l3 += x * w.w;
        }
#pragma unroll
        for (int m = 1; m < 8; m <<= 1) {
            l0 += __shfl_xor(l0, m, 64); l1 += __shfl_xor(l1, m, 64);
            l2 += __shfl_xor(l2, m, 64); l3 += __shfl_xor(l3, m, 64);
        }
        const float sc = 0.08838834764831845f; // 1/sqrt(128)
        l0 = (l0 + ws[WS_CK + 0]) * sc; l1 = (l1 + ws[WS_CK + 1]) * sc;
        l2 = (l2 + ws[WS_CK + 2]) * sc; l3 = (l3 + ws[WS_CK + 3]) * sc;
        float mx = fmaxf(fmaxf(l0, l1), fmaxf(l2, l3));
        float e0 = expf(l0 - mx), e1 = expf(l1 - mx), e2 = expf(l2 - mx), e3 = expf(l3 - mx);
        float inv = 1.f / (e0 + e1 + e2 + e3);
        int head = sub >> 1;
        float ar = ((head == 0) ? e0 : (head == 1) ? e1 : (head == 2) ? e2 : e3) * inv;

        // h2 = h + ar*pv  (this thread's 64 d's live in one head)
        const float4* pv4 = (const float4*)&ws[WS_VALS + sub * 64];
        float sum = 0.f, ssq = 0.f;
#pragma unroll
        for (int i = 0; i < 16; ++i) {
            float4 p = pv4[i];
            float a0 = hv[i * 4]     + ar * p.x;
            float a1 = hv[i * 4 + 1] + ar * p.y;
            float a2 = hv[i * 4 + 2] + ar * p.z;
            float a3 = hv[i * 4 + 3] + ar * p.w;
            hv[i * 4] = a0; hv[i * 4 + 1] = a1; hv[i * 4 + 2] = a2; hv[i * 4 + 3] = a3;
            sum += a0 + a1 + a2 + a3;
            ssq += a0 * a0 + a1 * a1 + a2 * a2 + a3 * a3;
        }
#pragma unroll
        for (int m = 1; m < 8; m <<= 1) {
            sum += __shfl_xor(sum, m, 64); ssq += __shfl_xor(ssq, m, 64);
        }
        float mean = sum * (1.f / 512.f);
        float var = ssq * (1.f / 512.f) - mean * mean;
        float rinv = rsqrtf(fmaxf(var, 0.f) + EPS);
        // normalize, split to bf16 hi/lo, write LDS
        const int d0 = sub * 64;
#pragma unroll
        for (int g = 0; g < 8; ++g) {
            float4 s2a = *(const float4*)&ln2s[d0 + g * 8];
            float4 s2b = *(const float4*)&ln2s[d0 + g * 8 + 4];
            float4 b2a = *(const float4*)&ln2b[d0 + g * 8];
            float4 b2b = *(const float4*)&ln2b[d0 + g * 8 + 4];
            float xs[8];
            xs[0] = (hv[g * 8]     - mean) * rinv * s2a.x + b2a.x;
            xs[1] = (hv[g * 8 + 1] - mean) * rinv * s2a.y + b2a.y;
            xs[2] = (hv[g * 8 + 2] - mean) * rinv * s2a.z + b2a.z;
            xs[3] = (hv[g * 8 + 3] - mean) * rinv * s2a.w + b2a.w;
            xs[4] = (hv[g * 8 + 4] - mean) * rinv * s2b.x + b2b.x;
            xs[5] = (hv[g * 8 + 5] - mean) * rinv * s2b.y + b2b.y;
            xs[6] = (hv[g * 8 + 6] - mean) * rinv * s2b.z + b2b.z;
            xs[7] = (hv[g * 8 + 7] - mean) * rinv * s2b.w + b2b.w;
            bf16x8 vh, vl;
#pragma unroll
            for (int e = 0; e < 8; ++e) {
                unsigned short hb = bf16_rne(xs[e]);
                vh[e] = (short)hb;
                vl[e] = (short)bf16_rne(xs[e] - bf16_to_f(hb));
            }
            *(bf16x8*)&Ahi[row * AP + d0 + g * 8] = vh;
            *(bf16x8*)&Alo[row * AP + d0 + g * 8] = vl;
        }
    }
    __syncthreads();

    // ---------------- phase 2: split-bf16 MFMA GEMM (64 x 512 x 512) ----------------
    const int w = t >> 6, l = t & 63;
    const int arow = l & 15, kgrp = l >> 4;
    f32x4 acc[4][4];
#pragma unroll
    for (int mt = 0; mt < 4; ++mt)
#pragma unroll
        for (int c = 0; c < 4; ++c) acc[mt][c] = (f32x4)(0.f);

    const unsigned short* BH = (const unsigned short*)&ws[WS_BH];
    const unsigned short* BL = (const unsigned short*)&ws[WS_BL];
    const int bb = (w * 4) * 512 + l * 8;

    for (int ks = 0; ks < 16; ++ks) {
        bf16x8 ah[4], al[4], bh[4], bl[4];
#pragma unroll
        for (int mt = 0; mt < 4; ++mt) {
            int off = (mt * 16 + arow) * AP + ks * 32 + kgrp * 8;
            ah[mt] = *(const bf16x8*)&Ahi[off];
            al[mt] = *(const bf16x8*)&Alo[off];
        }
#pragma unroll
        for (int c = 0; c < 4; ++c) {
            int fi = ks * 16384 + bb + c * 512;
            bh[c] = *(const bf16x8*)&BH[fi];
            bl[c] = *(const bf16x8*)&BL[fi];
        }
#pragma unroll
        for (int mt = 0; mt < 4; ++mt) {
#pragma unroll
            for (int c = 0; c < 4; ++c) {
                acc[mt][c] = __builtin_amdgcn_mfma_f32_16x16x32_bf16(ah[mt], bh[c], acc[mt][c], 0, 0, 0);
                acc[mt][c] = __builtin_amdgcn_mfma_f32_16x16x32_bf16(ah[mt], bl[c], acc[mt][c], 0, 0, 0);
                acc[mt][c] = __builtin_amdgcn_mfma_f32_16x16x32_bf16(al[mt], bh[c], acc[mt][c], 0, 0, 0);
            }
        }
    }

    // ---------------- phase 3: epilogue silu + residual + LN3 + store ----------------
    float bmv[4], s3v[4], b3v[4];
#pragma unroll
    for (int c = 0; c < 4; ++c) {
        int col = w * 64 + c * 16 + arow;
        bmv[c] = bm[col]; s3v[c] = ln3s[col]; b3v[c] = ln3b[col];
    }
    float sums[16], ssqs[16];
#pragma unroll
    for (int i = 0; i < 16; ++i) { sums[i] = 0.f; ssqs[i] = 0.f; }
#pragma unroll
    for (int mt = 0; mt < 4; ++mt) {
#pragma unroll
        for (int r = 0; r < 4; ++r) {
            int rloc = mt * 16 + kgrp * 4 + r;
#pragma unroll
            for (int c = 0; c < 4; ++c) {
                int col = w * 64 + c * 16 + arow;
                float h2 = bf16_to_f(Ahi[rloc * AP + col]) + bf16_to_f(Alo[rloc * AP + col]);
                float v = acc[mt][c][r] + bmv[c];
                float tv = h2 + silu_f(v);
                acc[mt][c][r] = tv;
                sums[mt * 4 + r] += tv;
                ssqs[mt * 4 + r] += tv * tv;
            }
        }
    }
#pragma unroll
    for (int m = 1; m < 16; m <<= 1) {
#pragma unroll
        for (int i = 0; i < 16; ++i) {
            sums[i] += __shfl_xor(sums[i], m, 64);
            ssqs[i] += __shfl_xor(ssqs[i], m, 64);
        }
    }
    if (arow == 0) {
#pragma unroll
        for (int mt = 0; mt < 4; ++mt)
#pragma unroll
            for (int r = 0; r < 4; ++r) {
                int rloc = mt * 16 + kgrp * 4 + r;
                rpart[rloc][w * 2] = sums[mt * 4 + r];
                rpart[rloc][w * 2 + 1] = ssqs[mt * 4 + r];
            }
    }
    __syncthreads();
#pragma unroll
    for (int mt = 0; mt < 4; ++mt) {
#pragma unroll
        for (int r = 0; r < 4; ++r) {
            int rloc = mt * 16 + kgrp * 4 + r;
            float s = 0.f, q = 0.f;
#pragma unroll
            for (int ww = 0; ww < 8; ++ww) {
                s += rpart[rloc][ww * 2];
                q += rpart[rloc][ww * 2 + 1];
            }
            float mean = s * (1.f / 512.f);
            float var = q * (1.f / 512.f) - mean * mean;
            float rinv = rsqrtf(fmaxf(var, 0.f) + EPS);
            int grow = rb + rloc;
            if (grow < N) {
#pragma unroll
                for (int c = 0; c < 4; ++c) {
                    int col = w * 64 + c * 16 + arow;
                    out[(size_t)grow * 512 + col] = (acc[mt][c][r] - mean) * rinv * s3v[c] + b3v[c];
                }
            }
        }
    }
}

// ============================================================ launcher
extern "C" void kernel_launch(void* const* d_in, const int* in_sizes, int n_in,
                              void* d_out, int out_size, void* d_ws, size_t ws_size,
                              hipStream_t stream) {
    const float* h    = (const float*)d_in[0];
    const float* rk   = (const float*)d_in[2];
    const float* Wq   = (const float*)d_in[3];
    const float* bq   = (const float*)d_in[4];
    const float* Wv   = (const float*)d_in[5];
    const float* bv   = (const float*)d_in[6];
    const float* lnrs = (const float*)d_in[7];
    const float* lnrb = (const float*)d_in[8];
    const float* ln1s = (const float*)d_in[9];
    const float* ln1b = (const float*)d_in[10];
    const float* W1   = (const float*)d_in[11];
    const float* b1   = (const float*)d_in[12];
    const float* W2   = (const float*)d_in[13];
    const float* b2   = (const float*)d_in[14];
    const float* W3   = (const float*)d_in[15];
    const float* b3   = (const float*)d_in[16];
    const float* Wk   = (const float*)d_in[17];
    const float* bk   = (const float*)d_in[18];
    const float* ln2s = (const float*)d_in[19];
    const float* ln2b = (const float*)d_in[20];
    const float* Wm   = (const float*)d_in[21];
    const float* bm   = (const float*)d_in[22];
    const float* ln3s = (const float*)d_in[23];
    const float* ln3b = (const float*)d_in[24];
    float* out = (float*)d_out;
    float* ws  = (float*)d_ws;
    const int N = in_sizes[0] / 512;

    k0_prep<<<1, 512, 0, stream>>>(Wq, bq, rk, ws);
    k3_conv<<<128, 256, 0, stream>>>(Wm, ws);
    k1_att<<<256, 256, 0, stream>>>(h, Wv, ws, N);
    k2a<<<1, 512, 0, stream>>>(bv, lnrs, lnrb, ln1s, ln1b, W1, b1, ws);
    k2b<<<16, 256, 0, stream>>>(W2, ws);
    k2c<<<32, 256, 0, stream>>>(b2, W3, ws);
    k2d<<<32, 256, 0, stream>>>(Wk, bk, b3, ws);
    k5_main<<<(N + 63) / 64, 512, 0, stream>>>(h, ws, ln2s, ln2b, bm, ln3s, ln3b, out, N);
}